// Round 2
// baseline (541.860 us; speedup 1.0000x reference)
//
#include <hip/hip_runtime.h>

#define NEG_INF -1e30f

constexpr int BLANKC = 6624;
constexpr int NCLS   = 6625;
constexpr int TT     = 512;
constexpr int LL     = 32;
constexpr int BB     = 32;

constexpr float L2E = 1.44269504088896340736f;  // log2(e)
constexpr float LN2 = 0.693147180559945309417f; // ln(2)

__device__ __forceinline__ float fast_exp2(float x) {
#if __has_builtin(__builtin_amdgcn_exp2f)
    return __builtin_amdgcn_exp2f(x);     // v_exp_f32 (native base-2)
#else
    return exp2f(x);
#endif
}
__device__ __forceinline__ float fast_log2(float x) {
#if __has_builtin(__builtin_amdgcn_logf)
    return __builtin_amdgcn_logf(x);      // v_log_f32 (native base-2)
#else
    return log2f(x);
#endif
}

// lane i <- lane i-1 (wave_shr:1); lane 0 <- NEG_INF via DPP "old" operand.
__device__ __forceinline__ float dpp_shr1(float x) {
#if __has_builtin(__builtin_amdgcn_update_dpp)
    return __int_as_float(__builtin_amdgcn_update_dpp(
        __float_as_int(NEG_INF), __float_as_int(x),
        0x138 /*wave_shr:1*/, 0xF, 0xF, false));
#else
    float r = __shfl_up(x, 1, 64);
    if ((int)(threadIdx.x & 63) == 0) r = NEG_INF;
    return r;
#endif
}

__device__ __forceinline__ float wave_allmax(float v) {
#pragma unroll
    for (int off = 32; off > 0; off >>= 1)
        v = fmaxf(v, __shfl_xor(v, off, 64));
    return v;
}
__device__ __forceinline__ float wave_allsum(float v) {
#pragma unroll
    for (int off = 32; off > 0; off >>= 1)
        v += __shfl_xor(v, off, 64);
    return v;
}

// one recursion step in base-2 logsumexp
__device__ __forceinline__ void ctc_step(float& alpha, float& a64,
                                         float e, float eb, bool allow) {
    float am1 = dpp_shr1(alpha);            // alpha[s-1] (lane0 -> NEG_INF)
    float am2 = dpp_shr1(am1);              // alpha[s-2] (lane0,1 -> NEG_INF)
    am2 = allow ? am2 : NEG_INF;
    const float aold = alpha;
    const float m  = fmaxf(fmaxf(aold, am1), am2);   // v_max3_f32
    const float r  = fast_exp2(aold - m) + fast_exp2(am1 - m) + fast_exp2(am2 - m);
    const float na = m + fast_log2(r) + e;
    // state-64 (blank sink): 2-way lse with this lane's own alpha; lane 63 true
    const float m2   = fmaxf(a64, aold);
    const float r2   = fast_exp2(a64 - m2) + fast_exp2(aold - m2);
    const float na64 = m2 + fast_log2(r2) + eb;
    alpha = na;
    a64   = na64;
}

// ---------------------------------------------------------------------------
// Fused kernel: one block per batch, 8 waves.
// Phase 1: each wave log2-normalizes 4 label columns into LDS (rotated by
//          +col so phase-2 reads at fixed t hit distinct banks); wave 0 also
//          normalizes the blank column (kept in regs + spilled to gblank for
//          broadcast chunk reloads).
// Phase 2: wave 0 runs the 511-step alpha recursion, register double-buffered
//          32-step chunks (labels from LDS, blank from L2-resident gblank).
// ---------------------------------------------------------------------------
__global__ __launch_bounds__(512) void ctc_fused(
    const float* __restrict__ x,              // [B, T, C]
    const int*   __restrict__ targets,        // [B, L]
    const int*   __restrict__ input_lengths,  // [B]
    const int*   __restrict__ target_lengths, // [B]
    float*       __restrict__ gblank,         // [B, TT] normalized blank col
    float*       __restrict__ part)           // [B]
{
    __shared__ float lcols[LL * TT];          // 32 cols x 512 = 64 KiB exactly

    const int b    = blockIdx.x;
    const int wave = threadIdx.x >> 6;
    const int lane = threadIdx.x & 63;
    const float* xb = x + (size_t)b * TT * NCLS;
    float* gb = gblank + (size_t)b * TT;

    // ---------------- phase 1 ----------------
    int cls[4];
#pragma unroll
    for (int i = 0; i < 4; ++i) cls[i] = targets[b * LL + (wave * 4 + i)];

    float vB[8];
    if (wave == 0) {
#pragma unroll
        for (int k = 0; k < 8; ++k)
            vB[k] = xb[(size_t)(lane + 64 * k) * NCLS + BLANKC];
    }
    float vL[4][8];
#pragma unroll
    for (int i = 0; i < 4; ++i) {
#pragma unroll
        for (int k = 0; k < 8; ++k)
            vL[i][k] = xb[(size_t)(lane + 64 * k) * NCLS + cls[i]];
    }
#pragma unroll
    for (int i = 0; i < 4; ++i) {
        const int col = wave * 4 + i;
        float m = NEG_INF;
#pragma unroll
        for (int k = 0; k < 8; ++k) m = fmaxf(m, vL[i][k]);
        m = wave_allmax(m);
        float w8[8];
        float s = 0.f;
#pragma unroll
        for (int k = 0; k < 8; ++k) { w8[k] = (vL[i][k] - m) * L2E; s += fast_exp2(w8[k]); }
        s = wave_allsum(s);
        const float ls = fast_log2(s);
#pragma unroll
        for (int k = 0; k < 8; ++k) {
            const int t = lane + 64 * k;
            lcols[col * TT + ((t + col) & (TT - 1))] = w8[k] - ls;  // rotated store
        }
    }
    float bl[8];
    if (wave == 0) {
        float m = NEG_INF;
#pragma unroll
        for (int k = 0; k < 8; ++k) m = fmaxf(m, vB[k]);
        m = wave_allmax(m);
        float s = 0.f;
#pragma unroll
        for (int k = 0; k < 8; ++k) { bl[k] = (vB[k] - m) * L2E; s += fast_exp2(bl[k]); }
        s = wave_allsum(s);
        const float ls = fast_log2(s);
#pragma unroll
        for (int k = 0; k < 8; ++k) { bl[k] -= ls; gb[lane + 64 * k] = bl[k]; }
    }
    __syncthreads();           // LDS visible + gblank stores drained (vmcnt 0)
    if (wave != 0) return;

    // ---------------- phase 2 (wave 0 only) ----------------
    const int s    = lane;              // state 0..63
    const int j    = s >> 1;
    const bool odd = (s & 1) != 0;
    const int colj = j;                 // label column index (odd lanes)
    const int cbase = colj * TT;

    const int tj = odd ? targets[b * LL + j] : BLANKC;
    const bool allow = odd && (tj != BLANKC) &&
                       (s == 1 || tj != targets[b * LL + j - 1]);

    const int ilen = input_lengths[b];
    const int tlen = target_lengths[b];
    const int nsteps = min(ilen, TT);

// label-column chunk from LDS (rotated addressing, conflict-free across lanes)
#define LOADE(E, c) do {                                                      \
    _Pragma("unroll")                                                         \
    for (int u = 0; u < 32; ++u) {                                            \
        const int t_ = ((c) << 5) + u;                                        \
        E[u] = lcols[cbase + ((t_ + colj) & (TT - 1))];                       \
    }                                                                         \
} while (0)

// blank chunk from global (all lanes same address -> broadcast, L2-hit)
#define LOADB(EBV, c) do {                                                    \
    const float4* __p = reinterpret_cast<const float4*>(gb + ((c) << 5));     \
    _Pragma("unroll")                                                         \
    for (int k = 0; k < 8; ++k) {                                             \
        float4 __t = __p[k];                                                  \
        EBV[4*k+0] = __t.x; EBV[4*k+1] = __t.y;                               \
        EBV[4*k+2] = __t.z; EBV[4*k+3] = __t.w;                               \
    }                                                                         \
} while (0)

#define CHUNKF(E, EBV, u0) do {                                               \
    _Pragma("unroll")                                                         \
    for (int u = (u0); u < 32; ++u) {                                         \
        const float eb_ = EBV[u];                                             \
        const float e_  = odd ? E[u] : eb_;                                   \
        ctc_step(alpha, a64, e_, eb_, allow);                                 \
    }                                                                         \
} while (0)

    float alpha;
    float a64 = NEG_INF;

    if (nsteps == TT) {
        float eA[32], eB[32], bA[32], bBuf[32];
        LOADE(eA, 0); LOADB(bA, 0);
        LOADE(eB, 1); LOADB(bBuf, 1);
        alpha = (s < 2) ? (odd ? eA[0] : bA[0]) : NEG_INF;   // t=0 init
        CHUNKF(eA, bA, 1);                   // chunk 0: t = 1..31
#pragma unroll 1
        for (int p = 1; p + 1 < 16; p += 2) {   // p = 1,3,...,13
            LOADE(eA, p + 1); LOADB(bA, p + 1);
            CHUNKF(eB, bBuf, 0);             // chunk p
            LOADE(eB, p + 2); LOADB(bBuf, p + 2);
            CHUNKF(eA, bA, 0);               // chunk p+1
        }
        CHUNKF(eB, bBuf, 0);                 // chunk 15
    } else {
        // generic path (bench always full-length; correctness fallback)
        const float eb0 = gb[0];
        alpha = (s < 2) ? (odd ? lcols[cbase + (colj & (TT - 1))] : eb0) : NEG_INF;
        for (int t = 1; t < nsteps; ++t) {
            const float eb = gb[t];
            const float e  = odd ? lcols[cbase + ((t + colj) & (TT - 1))] : eb;
            ctc_step(alpha, a64, e, eb, allow);
        }
    }

    const int idx1 = 2 * tlen;                    // final blank (may be 64)
    const int idx2 = max(2 * tlen - 1, 0);        // final label (<= 63)
    const float l1 = (idx1 >= 64) ? __shfl(a64, 63, 64) : __shfl(alpha, idx1, 64);
    const float l2 = __shfl(alpha, idx2, 64);
    const float mm = fmaxf(l1, l2);
    const float res2 = mm + fast_log2(fast_exp2(l1 - mm) + fast_exp2(l2 - mm));
    float loss = -LN2 * res2;                     // back to natural log
    if (loss > 1e20f) loss = 0.f;                 // zero_infinity
    loss /= (float)max(tlen, 1);
    if (s == 0) part[b] = loss;

#undef LOADE
#undef LOADB
#undef CHUNKF
}

// ---------------------------------------------------------------------------
// Reduce: mean over batch (d_out is poisoned each call -> must write).
// ---------------------------------------------------------------------------
__global__ __launch_bounds__(64) void ctc_reduce(
    const float* __restrict__ part, float* __restrict__ out)
{
    const int lane = threadIdx.x;
    float v = (lane < BB) ? part[lane] : 0.f;
#pragma unroll
    for (int off = 32; off > 0; off >>= 1) v += __shfl_xor(v, off, 64);
    if (lane == 0) out[0] = v / (float)BB;
}

extern "C" void kernel_launch(void* const* d_in, const int* in_sizes, int n_in,
                              void* d_out, int out_size, void* d_ws, size_t ws_size,
                              hipStream_t stream) {
    const float* lp      = (const float*)d_in[0];   // [B, T, C] fp32
    const int*   targets = (const int*)d_in[1];     // [B, L]
    const int*   ilen    = (const int*)d_in[2];     // [B]
    const int*   tlen    = (const int*)d_in[3];     // [B]
    float* out = (float*)d_out;

    float* gblank = (float*)d_ws;                   // [B, TT]
    float* part   = (float*)d_ws + (size_t)BB * TT; // [B]

    ctc_fused<<<BB, 512, 0, stream>>>(lp, targets, ilen, tlen, gblank, part);
    ctc_reduce<<<1, 64, 0, stream>>>(part, out);
}